// Round 9
// baseline (849.569 us; speedup 1.0000x reference)
//
#include <hip/hip_runtime.h>
#include <hip/hip_bf16.h>

#define BATCH 2
#define SEQ 2048
#define HID 4096
#define NHEAD 32
#define HDIM 128
#define BH (BATCH*NHEAD)   /* 64 */
#define MROWS (BATCH*SEQ)  /* 4096 */
#define SC2 0.1275187963f   /* (1/sqrt(128)) * log2(e), folded into Q in rope */

typedef __attribute__((ext_vector_type(8))) short bf16x8;
typedef __attribute__((ext_vector_type(4))) float f32x4;

__device__ __forceinline__ float bf2f(short x){
  union { float f; unsigned u; } v; v.u = ((unsigned)(unsigned short)x) << 16; return v.f;
}
__device__ __forceinline__ short f2bf(float f){
  union { float f; unsigned u; } v; v.f = f;
  unsigned r = v.u + 0x7fffu + ((v.u >> 16) & 1u);
  return (short)(r >> 16);
}
__device__ __forceinline__ void gload_lds16(const void* g, void* l){
  __builtin_amdgcn_global_load_lds(
    (const __attribute__((address_space(1))) void*)g,
    (__attribute__((address_space(3))) void*)l, 16, 0, 0);
}

// ---------------- fused f32 -> bf16 convert (3 tensors) ----------------
__global__ void cvt3_bf16(const float* __restrict__ a, short* __restrict__ ao, int na4,
                          const float* __restrict__ b, short* __restrict__ bo, int nb4,
                          const float* __restrict__ cc, short* __restrict__ co, int nc4){
  int i = blockIdx.x*blockDim.x + threadIdx.x;
  int stride = gridDim.x*blockDim.x;
  int tot = na4 + nb4 + nc4;
  for (; i < tot; i += stride){
    const float* src; short* dst; int k = i;
    if (k < na4){ src=a; dst=ao; }
    else if (k < na4+nb4){ k -= na4; src=b; dst=bo; }
    else { k -= na4+nb4; src=cc; dst=co; }
    float4 v = ((const float4*)src)[k];
    short4 o;
    o.x = f2bf(v.x); o.y = f2bf(v.y); o.z = f2bf(v.z); o.w = f2bf(v.w);
    ((short4*)dst)[k] = o;
  }
}

// ---------------- RoPE cos/sin table ----------------
__global__ void rope_table_k(const int* __restrict__ pos, float* __restrict__ tab){
  int idx = blockIdx.x*blockDim.x + threadIdx.x;
  if (idx >= SEQ*64) return;
  int s = idx >> 6, d = idx & 63;
  float p = (float)pos[s];
  float inv = exp2f(-(float)d * (13.287712379549449f/64.0f)); // 10000^(-d/64)
  float ang = p * inv;
  tab[2*idx]   = cosf(ang);
  tab[2*idx+1] = sinf(ang);
}

// ===== 256x256 8-phase GEMM, reads {8,0,8,8}/phase, vmcnt(6) at ph3/ph7 =====
// LDS: [256 rows][64 cols] bf16 per operand, XOR-swizzled:
// phys_byte(row, colbyte) = row*128 + (colbyte ^ ((row&7)<<4)).
template<int W>
__device__ __forceinline__ void stage_half(const short* __restrict__ gsrc, int ldg,
                                           short* lds, int tid, int h){
  #pragma unroll
  for (int li=0; li<2; ++li){
    int e16 = li*512 + tid;
    int rs = e16 >> 3, ck = e16 & 7;
    int r = ((rs/W)*2 + h)*W + (rs%W);
    gload_lds16(gsrc + (size_t)r*ldg + ((ck ^ (r&7))<<3),
                lds + r*64 + ck*8);
  }
}

__device__ __forceinline__ void read_ahalf(const short* Asb, int wr, int c, int g,
                                           int Mh, bf16x8 (&afr)[4][2]){
  #pragma unroll
  for (int mi=0; mi<4; ++mi){
    int row = wr*128 + (Mh*4+mi)*16 + c;
    const char* bp = (const char*)Asb + row*128;
    #pragma unroll
    for (int kk=0; kk<2; ++kk)
      afr[mi][kk] = *(const bf16x8*)(bp + ((kk*64 + g*16) ^ ((row&7)<<4)));
  }
}
__device__ __forceinline__ void read_bhalf(const short* Bsb, int wc, int c, int g,
                                           int Nh, bf16x8 (&bfr)[2][2]){
  #pragma unroll
  for (int ni=0; ni<2; ++ni){
    int row = wc*64 + (Nh*2+ni)*16 + c;
    const char* bp = (const char*)Bsb + row*128;
    #pragma unroll
    for (int kk=0; kk<2; ++kk)
      bfr[ni][kk] = *(const bf16x8*)(bp + ((kk*64 + g*16) ^ ((row&7)<<4)));
  }
}
template<int MH, int NHH>
__device__ __forceinline__ void mma_q(bf16x8 (&afr)[4][2], bf16x8 (&bfr)[2][2],
                                      f32x4 (&acc)[8][4]){
  #pragma unroll
  for (int kk=0; kk<2; ++kk)
    #pragma unroll
    for (int mi=0; mi<4; ++mi)
      #pragma unroll
      for (int ni=0; ni<2; ++ni)
        acc[MH*4+mi][NHH*2+ni] = __builtin_amdgcn_mfma_f32_16x16x32_bf16(
            afr[mi][kk], bfr[ni][kk], acc[MH*4+mi][NHH*2+ni], 0,0,0);
}

#define BAR()  asm volatile("s_barrier" ::: "memory")
#define LGK0() asm volatile("s_waitcnt lgkmcnt(0)" ::: "memory")
#define VMC6() asm volatile("s_waitcnt vmcnt(6)" ::: "memory")
#define VMC8() asm volatile("s_waitcnt vmcnt(8)" ::: "memory")
#define VMC0() asm volatile("s_waitcnt vmcnt(0)" ::: "memory")
#define SP1()  __builtin_amdgcn_s_setprio(1)
#define SP0()  __builtin_amdgcn_s_setprio(0)

// MODE 0: QKV proj -> clip +-8 -> scatter bf16 into Q/K/V [BH][S][HD]
// MODE 1: O proj -> f32 row-major out
template<int MODE>
__global__ __launch_bounds__(512, 2) void gemm8s(
    const short* __restrict__ A, const short* __restrict__ Bw,
    short* __restrict__ Qb, short* __restrict__ Kb, short* __restrict__ Vb,
    float* __restrict__ Of){
  __shared__ __align__(16) short As[2][256*64];
  __shared__ __align__(16) short Bs[2][256*64];
  const int K = HID;
  int tid = threadIdx.x, lane = tid & 63, w = tid >> 6;
  int wr = w >> 2, wc = w & 3, g = lane >> 4, c = lane & 15;
  int gx = gridDim.x;
  int nwg = gx * gridDim.y;
  int bid = blockIdx.y*gx + blockIdx.x;
  int cpx = nwg >> 3;
  int swz = (bid & 7)*cpx + (bid >> 3);
  int m0 = (swz / gx) * 256, n0 = (swz % gx) * 256;

  const short* Abase = A  + (size_t)m0*K;
  const short* Bbase = Bw + (size_t)n0*K;
  auto stageA = [&](int buf, int kt, int h){
    stage_half<64>(Abase + kt*64, K, &As[buf][0], tid, h);
  };
  auto stageB = [&](int buf, int kt, int h){
    stage_half<32>(Bbase + kt*64, K, &Bs[buf][0], tid, h);
  };

  f32x4 acc[8][4];
  f32x4 zero = {0.f,0.f,0.f,0.f};
  #pragma unroll
  for (int i=0;i<8;++i)
    #pragma unroll
    for (int j=0;j<4;++j) acc[i][j] = zero;
  bf16x8 afr[4][2], bfr0[2][2], bfr1[2][2];

  // prologue: stage t0 then t1; drain t0; preload B0N0/B0N1
  stageB(0,0,0); stageB(0,0,1); stageA(0,0,0); stageA(0,0,1);
  stageB(1,1,0); stageB(1,1,1); stageA(1,1,0); stageA(1,1,1);
  VMC8();
  BAR();
  read_bhalf(&Bs[0][0], wc,c,g, 0, bfr0);
  read_bhalf(&Bs[0][0], wc,c,g, 1, bfr1);

  const int NITER = K/128;  // 32 iterations, 2 K-tiles each
  for (int i = 0; i < NITER-1; ++i){
    int t2 = 2*i+2, t3 = 2*i+3;
    // ph1: read A0h0; mma M0N0(afr,bfr0)
    read_ahalf(&As[0][0], wr,c,g, 0, afr);
    BAR(); LGK0(); SP1(); mma_q<0,0>(afr,bfr0,acc); SP0(); BAR();
    // ph2: stage B0h0(t2); mma M0N1(afr,bfr1)  [pure MFMA + stage]
    stageB(0, t2, 0);
    BAR(); LGK0(); SP1(); mma_q<0,1>(afr,bfr1,acc); SP0(); BAR();
    // ph3: read A0h1; stage B0h1+A0h0(t2); mma M1N1; drain t1 (vmcnt 6)
    read_ahalf(&As[0][0], wr,c,g, 1, afr);
    stageB(0, t2, 1); stageA(0, t2, 0);
    BAR(); LGK0(); SP1(); mma_q<1,1>(afr,bfr1,acc); SP0(); VMC6(); BAR();
    // ph4: pre-read bfr1<-B1N1; mma M1N0(afr,bfr0); post-read bfr0<-B1N0
    read_bhalf(&Bs[1][0], wc,c,g, 1, bfr1);
    BAR(); LGK0(); SP1(); mma_q<1,0>(afr,bfr0,acc); SP0();
    read_bhalf(&Bs[1][0], wc,c,g, 0, bfr0);
    BAR();
    // ph5: read A1h0; stage A0h1(t2); mma M0N0(afr,bfr0)
    read_ahalf(&As[1][0], wr,c,g, 0, afr);
    stageA(0, t2, 1);
    BAR(); LGK0(); SP1(); mma_q<0,0>(afr,bfr0,acc); SP0(); BAR();
    // ph6: stage B1h0(t3); mma M0N1(afr,bfr1)
    stageB(1, t3, 0);
    BAR(); LGK0(); SP1(); mma_q<0,1>(afr,bfr1,acc); SP0(); BAR();
    // ph7: read A1h1; stage B1h1+A1h0(t3); mma M1N1; drain t2 (vmcnt 6)
    read_ahalf(&As[1][0], wr,c,g, 1, afr);
    stageB(1, t3, 1); stageA(1, t3, 0);
    BAR(); LGK0(); SP1(); mma_q<1,1>(afr,bfr1,acc); SP0(); VMC6(); BAR();
    // ph8: stage A1h1(t3); pre-read bfr1<-B0N1(t2); mma M1N0; post-read bfr0<-B0N0(t2)
    stageA(1, t3, 1);
    read_bhalf(&Bs[0][0], wc,c,g, 1, bfr1);
    BAR(); LGK0(); SP1(); mma_q<1,0>(afr,bfr0,acc); SP0();
    read_bhalf(&Bs[0][0], wc,c,g, 0, bfr0);
    BAR();
  }
  { // peeled final iteration (tiles NT-2 in buf0, NT-1 in buf1): no staging
    read_ahalf(&As[0][0], wr,c,g, 0, afr);
    BAR(); LGK0(); SP1(); mma_q<0,0>(afr,bfr0,acc); SP0(); BAR();
    BAR(); LGK0(); SP1(); mma_q<0,1>(afr,bfr1,acc); SP0(); BAR();
    read_ahalf(&As[0][0], wr,c,g, 1, afr);
    BAR(); LGK0(); SP1(); mma_q<1,1>(afr,bfr1,acc); SP0(); VMC0(); BAR();
    read_bhalf(&Bs[1][0], wc,c,g, 1, bfr1);
    BAR(); LGK0(); SP1(); mma_q<1,0>(afr,bfr0,acc); SP0();
    read_bhalf(&Bs[1][0], wc,c,g, 0, bfr0);
    BAR();
    read_ahalf(&As[1][0], wr,c,g, 0, afr);
    BAR(); LGK0(); SP1(); mma_q<0,0>(afr,bfr0,acc); SP0(); BAR();
    BAR(); LGK0(); SP1(); mma_q<0,1>(afr,bfr1,acc); SP0(); BAR();
    read_ahalf(&As[1][0], wr,c,g, 1, afr);
    BAR(); LGK0(); SP1(); mma_q<1,1>(afr,bfr1,acc); SP0(); BAR();
    BAR(); LGK0(); SP1(); mma_q<1,0>(afr,bfr0,acc); SP0(); BAR();
  }

  // epilogue
  #pragma unroll
  for (int fa=0; fa<8; ++fa){
    #pragma unroll
    for (int fb=0; fb<4; ++fb){
      f32x4 v = acc[fa][fb];
      #pragma unroll
      for (int rr=0; rr<4; ++rr){
        int row = m0 + wr*128 + fa*16 + g*4 + rr;
        int col = n0 + wc*64  + fb*16 + c;
        float x = v[rr];
        if (MODE == 0){
          x = fminf(fmaxf(x, -8.0f), 8.0f);
          int sel = col >> 12, wi = col & 4095;
          int head = wi >> 7, d = wi & 127;
          int b = row >> 11, s = row & 2047;
          size_t off = ((size_t)(b*NHEAD + head)*SEQ + s)*HDIM + d;
          short* dst = (sel == 0) ? Qb : (sel == 1) ? Kb : Vb;
          dst[off] = f2bf(x);
        } else {
          Of[(size_t)row*HID + col] = x;
        }
      }
    }
  }
}

// ---- RoPE in place on Q and K, vectorized; Q gets *SC2 (scale+log2e fold) ----
__global__ void rope_apply_k(short* __restrict__ Qb, short* __restrict__ Kb,
                             const float* __restrict__ tab){
  int idx = blockIdx.x*blockDim.x + threadIdx.x;
  if (idx >= BH*SEQ*8) return;
  int t = idx & 7;
  int s = (idx >> 3) & (SEQ-1);
  int bh = idx >> 14;
  size_t base = ((size_t)bh*SEQ + s)*HDIM + t*8;
  const float* tb = tab + 2*(s*64 + t*8);
  bf16x8 q1 = *(bf16x8*)(Qb+base), q2 = *(bf16x8*)(Qb+base+64);
  bf16x8 k1 = *(bf16x8*)(Kb+base), k2 = *(bf16x8*)(Kb+base+64);
  bf16x8 o1, o2, p1, p2;
  #pragma unroll
  for (int u=0;u<8;++u){
    float cs = tb[2*u], sn = tb[2*u+1];
    float a = bf2f(q1[u]), b = bf2f(q2[u]);
    o1[u] = f2bf((a*cs - b*sn)*SC2); o2[u] = f2bf((b*cs + a*sn)*SC2);
    a = bf2f(k1[u]); b = bf2f(k2[u]);
    p1[u] = f2bf(a*cs - b*sn); p2[u] = f2bf(b*cs + a*sn);
  }
  *(bf16x8*)(Qb+base)    = o1; *(bf16x8*)(Qb+base+64) = o2;
  *(bf16x8*)(Kb+base)    = p1; *(bf16x8*)(Kb+base+64) = p2;
}

// ---------------- V transpose: [BH][S][HD] -> Vt [BH][HD][S] ----------------
__global__ void transpose_v_k(const short* __restrict__ V, short* __restrict__ Vt){
  __shared__ short t[32][33];
  int bh = blockIdx.z;
  int s0 = blockIdx.x*32, d0 = blockIdx.y*32;
  int tx = threadIdx.x & 31, ty = threadIdx.x >> 5;  // 32 x 8
  const short* src = V + ((size_t)bh*SEQ + s0)*HDIM + d0;
  #pragma unroll
  for (int i=ty;i<32;i+=8) t[i][tx] = src[(size_t)i*HDIM + tx];
  __syncthreads();
  short* dst = Vt + ((size_t)bh*HDIM + d0)*SEQ + s0;
  #pragma unroll
  for (int i=ty;i<32;i+=8) dst[(size_t)i*SEQ + tx] = t[tx][i];
}

// ---- Flash attention, causal, double-buffered; base-2 softmax + defer-rescale ----
__global__ __launch_bounds__(256) void flash_attn_k(
    const short* __restrict__ Qb, const short* __restrict__ Kb,
    const short* __restrict__ Vt, short* __restrict__ attn){
  __shared__ short Ks[2][64*128];   // [kv][d], chunk-swizzled
  __shared__ short Vs[2][128*64];   // [d][kv], chunk-swizzled
  __shared__ short Ps[4][16][72];   // per-wave P, padded stride 72
  int tid = threadIdx.x, lane = tid & 63, w = tid >> 6;
  int g = lane >> 4, c = lane & 15;
  int flat = blockIdx.y*gridDim.x + blockIdx.x;
  int xcd = flat & 7, idx = flat >> 3;
  int bh = xcd + 8*(idx >> 5);
  int qblk = 31 - (idx & 31);       // heavy-first
  int q0 = qblk * 64;
  int qw = q0 + w*16;
  bf16x8 qf[4];
  #pragma unroll
  for (int ks=0;ks<4;++ks)
    qf[ks] = *(const bf16x8*)(Qb + ((size_t)bh*SEQ + qw + c)*HDIM + ks*32 + g*8);
  f32x4 o[8];
  f32x4 zero = {0.f,0.f,0.f,0.f};
  #pragma unroll
  for (int i=0;i<8;++i) o[i] = zero;
  float m_r[4] = {-1e30f,-1e30f,-1e30f,-1e30f};
  float l_r[4] = {0.f,0.f,0.f,0.f};

  auto stage = [&](int j, int b){
    int kv0 = j*64;
    #pragma unroll
    for (int i=0;i<4;++i){
      int e = i*256 + tid;
      int kr = e >> 4, kc = e & 15;
      gload_lds16(Kb + ((size_t)bh*SEQ + kv0 + kr)*HDIM + (size_t)((kc ^ (kr&7))*8),
                  &Ks[b][kr*128 + kc*8]);
      int vr = e >> 3, vc = e & 7;
      gload_lds16(Vt + ((size_t)bh*HDIM + vr)*SEQ + kv0 + (size_t)((vc ^ (vr&7))*8),
                  &Vs[b][vr*64 + vc*8]);
    }
  };

  stage(0, 0);
  __syncthreads();
  int buf = 0;
  for (int j=0;j<=qblk;++j){
    if (j < qblk) stage(j+1, buf^1);

    int kv0 = j*64;
    f32x4 sf[4];
    #pragma unroll
    for (int fj=0;fj<4;++fj) sf[fj] = zero;
    __builtin_amdgcn_s_setprio(1);
    #pragma unroll
    for (int ks=0;ks<4;++ks){
      #pragma unroll
      for (int fj=0;fj<4;++fj){
        int kvrow = fj*16 + c;
        bf16x8 kb = *(const bf16x8*)&Ks[buf][kvrow*128 + (((ks*4+g) ^ (c&7))*8)];
        sf[fj] = __builtin_amdgcn_mfma_f32_16x16x32_bf16(qf[ks], kb, sf[fj], 0,0,0);
      }
    }
    __builtin_amdgcn_s_setprio(0);
    bool diag = (j == qblk);
    float rmax[4];
    #pragma unroll
    for (int rr=0;rr<4;++rr){
      if (diag){
        #pragma unroll
        for (int fj=0;fj<4;++fj)
          if ((kv0 + fj*16 + c) > (qw + g*4 + rr)) sf[fj][rr] = -1e30f;
      }
      float t = fmaxf(fmaxf(sf[0][rr], sf[1][rr]), fmaxf(sf[2][rr], sf[3][rr]));
      t = fmaxf(t, __shfl_xor(t, 1));
      t = fmaxf(t, __shfl_xor(t, 2));
      t = fmaxf(t, __shfl_xor(t, 4));
      t = fmaxf(t, __shfl_xor(t, 8));
      rmax[rr] = t;
    }
    // T13 defer-rescale: skip O/l rescale while per-tile max growth < 8 (base-2)
    bool need = (rmax[0] > m_r[0] + 8.0f) | (rmax[1] > m_r[1] + 8.0f) |
                (rmax[2] > m_r[2] + 8.0f) | (rmax[3] > m_r[3] + 8.0f);
    if (__any(need)){
      float alpha[4];
      #pragma unroll
      for (int rr=0;rr<4;++rr){
        float mnew = fmaxf(m_r[rr], rmax[rr]);
        alpha[rr] = exp2f(m_r[rr] - mnew);
        m_r[rr] = mnew;
        l_r[rr] *= alpha[rr];
      }
      #pragma unroll
      for (int ni=0;ni<8;++ni){
        f32x4 t = o[ni];
        t[0]*=alpha[0]; t[1]*=alpha[1]; t[2]*=alpha[2]; t[3]*=alpha[3];
        o[ni] = t;
      }
    }
    #pragma unroll
    for (int rr=0;rr<4;++rr){
      float ps = 0.f;
      #pragma unroll
      for (int fj=0;fj<4;++fj){
        float p = exp2f(sf[fj][rr] - m_r[rr]);
        sf[fj][rr] = p;
        ps += p;
      }
      ps += __shfl_xor(ps, 1);
      ps += __shfl_xor(ps, 2);
      ps += __shfl_xor(ps, 4);
      ps += __shfl_xor(ps, 8);
      l_r[rr] += ps;
    }
    #pragma unroll
    for (int fj=0;fj<4;++fj)
      #pragma unroll
      for (int rr=0;rr<4;++rr)
        Ps[w][g*4+rr][fj*16+c] = f2bf(sf[fj][rr]);
    __builtin_amdgcn_s_setprio(1);
    #pragma unroll
    for (int ks=0;ks<2;++ks){
      bf16x8 pa = *(const bf16x8*)&Ps[w][c][ks*32 + g*8];
      #pragma unroll
      for (int ni=0;ni<8;++ni){
        int d = ni*16 + c;
        bf16x8 vb = *(const bf16x8*)&Vs[buf][d*64 + (((ks*4+g) ^ (c&7))*8)];
        o[ni] = __builtin_amdgcn_mfma_f32_16x16x32_bf16(pa, vb, o[ni], 0,0,0);
      }
    }
    __builtin_amdgcn_s_setprio(0);
    __syncthreads();
    buf ^= 1;
  }
  int b = bh >> 5, h = bh & 31;
  #pragma unroll
  for (int rr=0;rr<4;++rr){
    float inv = 1.0f / l_r[rr];
    int s = qw + g*4 + rr;
    #pragma unroll
    for (int ni=0;ni<8;++ni){
      int d = ni*16 + c;
      attn[((size_t)(b*SEQ + s))*HID + h*HDIM + d] = f2bf(o[ni][rr] * inv);
    }
  }
}

extern "C" void kernel_launch(void* const* d_in, const int* in_sizes, int n_in,
                              void* d_out, int out_size, void* d_ws, size_t ws_size,
                              hipStream_t stream){
  const float* hs   = (const float*)d_in[0];
  const int*   pos  = (const int*)d_in[1];
  const float* wqkv = (const float*)d_in[2];
  const float* wo   = (const float*)d_in[3];
  float* out = (float*)d_out;
  char* ws = (char*)d_ws;
  size_t off = 0;
  auto alloc = [&](size_t bytes){ void* p = ws + off; off += (bytes + 255) & ~(size_t)255; return p; };
  short* hsb   = (short*)alloc((size_t)MROWS*HID*2);
  short* wqkvb = (short*)alloc((size_t)3*HID*HID*2);
  short* wob   = (short*)alloc((size_t)HID*HID*2);
  short* Qb    = (short*)alloc((size_t)BH*SEQ*HDIM*2);
  short* Kb    = (short*)alloc((size_t)BH*SEQ*HDIM*2);
  short* Vb    = (short*)alloc((size_t)BH*SEQ*HDIM*2);
  short* Vt    = (short*)alloc((size_t)BH*SEQ*HDIM*2);
  short* attn  = (short*)alloc((size_t)MROWS*HID*2);
  float* tab   = (float*)alloc((size_t)SEQ*64*2*4);
  (void)ws_size; (void)in_sizes; (void)n_in; (void)out_size;

  cvt3_bf16<<<2048,256,0,stream>>>(hs, hsb, MROWS*HID/4,
                                   wqkv, wqkvb, 3*HID*HID/4,
                                   wo, wob, HID*HID/4);
  rope_table_k<<<(SEQ*64+255)/256,256,0,stream>>>(pos, tab);
  gemm8s<0><<<dim3(48,16),512,0,stream>>>(hsb, wqkvb, Qb, Kb, Vb, nullptr);
  rope_apply_k<<<(BH*SEQ*8+255)/256,256,0,stream>>>(Qb, Kb, tab);
  transpose_v_k<<<dim3(SEQ/32, HDIM/32, BH),256,0,stream>>>(Vb, Vt);
  flash_attn_k<<<dim3(SEQ/64, BH),256,0,stream>>>(Qb, Kb, Vt, attn);
  gemm8s<1><<<dim3(16,16),512,0,stream>>>(attn, wob, nullptr, nullptr, nullptr, out);
}

// Round 10
// 820.722 us; speedup vs baseline: 1.0351x; 1.0351x over previous
//
#include <hip/hip_runtime.h>
#include <hip/hip_bf16.h>

#define BATCH 2
#define SEQ 2048
#define HID 4096
#define NHEAD 32
#define HDIM 128
#define BH (BATCH*NHEAD)   /* 64 */
#define MROWS (BATCH*SEQ)  /* 4096 */
#define SC2 0.1275187963f   /* (1/sqrt(128)) * log2(e), folded into Q in rope */

typedef __attribute__((ext_vector_type(8))) short bf16x8;
typedef __attribute__((ext_vector_type(4))) float f32x4;

__device__ __forceinline__ float bf2f(short x){
  union { float f; unsigned u; } v; v.u = ((unsigned)(unsigned short)x) << 16; return v.f;
}
__device__ __forceinline__ short f2bf(float f){
  union { float f; unsigned u; } v; v.f = f;
  unsigned r = v.u + 0x7fffu + ((v.u >> 16) & 1u);
  return (short)(r >> 16);
}
__device__ __forceinline__ void gload_lds16(const void* g, void* l){
  __builtin_amdgcn_global_load_lds(
    (const __attribute__((address_space(1))) void*)g,
    (__attribute__((address_space(3))) void*)l, 16, 0, 0);
}

// ---------------- fused f32 -> bf16 convert (3 tensors) ----------------
__global__ void cvt3_bf16(const float* __restrict__ a, short* __restrict__ ao, int na4,
                          const float* __restrict__ b, short* __restrict__ bo, int nb4,
                          const float* __restrict__ cc, short* __restrict__ co, int nc4){
  int i = blockIdx.x*blockDim.x + threadIdx.x;
  int stride = gridDim.x*blockDim.x;
  int tot = na4 + nb4 + nc4;
  for (; i < tot; i += stride){
    const float* src; short* dst; int k = i;
    if (k < na4){ src=a; dst=ao; }
    else if (k < na4+nb4){ k -= na4; src=b; dst=bo; }
    else { k -= na4+nb4; src=cc; dst=co; }
    float4 v = ((const float4*)src)[k];
    short4 o;
    o.x = f2bf(v.x); o.y = f2bf(v.y); o.z = f2bf(v.z); o.w = f2bf(v.w);
    ((short4*)dst)[k] = o;
  }
}

// ---------------- RoPE cos/sin table ----------------
__global__ void rope_table_k(const int* __restrict__ pos, float* __restrict__ tab){
  int idx = blockIdx.x*blockDim.x + threadIdx.x;
  if (idx >= SEQ*64) return;
  int s = idx >> 6, d = idx & 63;
  float p = (float)pos[s];
  float inv = exp2f(-(float)d * (13.287712379549449f/64.0f)); // 10000^(-d/64)
  float ang = p * inv;
  tab[2*idx]   = cosf(ang);
  tab[2*idx+1] = sinf(ang);
}

// ===== 256x256 8-phase GEMM, minimal LDS reads (24 b128/K-tile), vmcnt(6/8) =====
// (round-5 known-good: 395us QKV, MfmaUtil 45.5, 0 bank conflicts, no spill.
//  Schedule is a verified local optimum: r7 read-ahead spilled, r9 {8,0,8,8} lost 7%.)
template<int W>
__device__ __forceinline__ void stage_half(const short* __restrict__ gsrc, int ldg,
                                           short* lds, int tid, int h){
  #pragma unroll
  for (int li=0; li<2; ++li){
    int e16 = li*512 + tid;
    int rs = e16 >> 3, ck = e16 & 7;
    int r = ((rs/W)*2 + h)*W + (rs%W);
    gload_lds16(gsrc + (size_t)r*ldg + ((ck ^ (r&7))<<3),
                lds + r*64 + ck*8);
  }
}

__device__ __forceinline__ void read_ahalf(const short* Asb, int wr, int c, int g,
                                           int Mh, bf16x8 (&afr)[4][2]){
  #pragma unroll
  for (int mi=0; mi<4; ++mi){
    int row = wr*128 + (Mh*4+mi)*16 + c;
    const char* bp = (const char*)Asb + row*128;
    #pragma unroll
    for (int kk=0; kk<2; ++kk)
      afr[mi][kk] = *(const bf16x8*)(bp + ((kk*64 + g*16) ^ ((row&7)<<4)));
  }
}
__device__ __forceinline__ void read_bhalf(const short* Bsb, int wc, int c, int g,
                                           int Nh, bf16x8 (&bfr)[2][2]){
  #pragma unroll
  for (int ni=0; ni<2; ++ni){
    int row = wc*64 + (Nh*2+ni)*16 + c;
    const char* bp = (const char*)Bsb + row*128;
    #pragma unroll
    for (int kk=0; kk<2; ++kk)
      bfr[ni][kk] = *(const bf16x8*)(bp + ((kk*64 + g*16) ^ ((row&7)<<4)));
  }
}
template<int MH, int NHH>
__device__ __forceinline__ void mma_q(bf16x8 (&afr)[4][2], bf16x8 (&bfr)[2][2],
                                      f32x4 (&acc)[8][4]){
  #pragma unroll
  for (int kk=0; kk<2; ++kk)
    #pragma unroll
    for (int mi=0; mi<4; ++mi)
      #pragma unroll
      for (int ni=0; ni<2; ++ni)
        acc[MH*4+mi][NHH*2+ni] = __builtin_amdgcn_mfma_f32_16x16x32_bf16(
            afr[mi][kk], bfr[ni][kk], acc[MH*4+mi][NHH*2+ni], 0,0,0);
}

#define BAR()  asm volatile("s_barrier" ::: "memory")
#define LGK0() asm volatile("s_waitcnt lgkmcnt(0)" ::: "memory")
#define VMC6() asm volatile("s_waitcnt vmcnt(6)" ::: "memory")
#define VMC8() asm volatile("s_waitcnt vmcnt(8)" ::: "memory")
#define VMC0() asm volatile("s_waitcnt vmcnt(0)" ::: "memory")
#define SP1()  __builtin_amdgcn_s_setprio(1)
#define SP0()  __builtin_amdgcn_s_setprio(0)

// MODE 0: QKV proj -> clip +-8 -> scatter bf16 into Q/K/V [BH][S][HD]
// MODE 1: O proj -> f32 row-major out
template<int MODE>
__global__ __launch_bounds__(512, 2) void gemm8r(
    const short* __restrict__ A, const short* __restrict__ Bw,
    short* __restrict__ Qb, short* __restrict__ Kb, short* __restrict__ Vb,
    float* __restrict__ Of){
  __shared__ __align__(16) short As[2][256*64];
  __shared__ __align__(16) short Bs[2][256*64];
  const int K = HID;
  int tid = threadIdx.x, lane = tid & 63, w = tid >> 6;
  int wr = w >> 2, wc = w & 3, g = lane >> 4, c = lane & 15;
  int gx = gridDim.x;
  int nwg = gx * gridDim.y;
  int bid = blockIdx.y*gx + blockIdx.x;
  int cpx = nwg >> 3;
  int swz = (bid & 7)*cpx + (bid >> 3);
  int m0 = (swz / gx) * 256, n0 = (swz % gx) * 256;

  const short* Abase = A  + (size_t)m0*K;
  const short* Bbase = Bw + (size_t)n0*K;
  auto stageA = [&](int buf, int kt, int h){
    stage_half<64>(Abase + kt*64, K, &As[buf][0], tid, h);
  };
  auto stageB = [&](int buf, int kt, int h){
    stage_half<32>(Bbase + kt*64, K, &Bs[buf][0], tid, h);
  };

  f32x4 acc[8][4];
  f32x4 zero = {0.f,0.f,0.f,0.f};
  #pragma unroll
  for (int i=0;i<8;++i)
    #pragma unroll
    for (int j=0;j<4;++j) acc[i][j] = zero;
  bf16x8 afr[4][2], bfr0[2][2], bfr1[2][2];

  stageB(0,0,0); stageB(0,0,1); stageA(0,0,0); stageA(0,0,1);
  stageB(1,1,0); stageB(1,1,1); stageA(1,1,0); stageA(1,1,1);
  VMC8();
  BAR();

  const int NITER = K/128;  // 32 iterations, 2 K-tiles each
  for (int i = 0; i < NITER-1; ++i){
    int t2 = 2*i+2, t3 = 2*i+3;
    read_ahalf(&As[0][0], wr,c,g, 0, afr);
    read_bhalf(&Bs[0][0], wc,c,g, 0, bfr0);
    BAR(); LGK0(); SP1(); mma_q<0,0>(afr,bfr0,acc); SP0(); BAR();
    read_bhalf(&Bs[0][0], wc,c,g, 1, bfr1);
    stageB(0, t2, 0);
    BAR(); LGK0(); SP1(); mma_q<0,1>(afr,bfr1,acc); SP0(); BAR();
    read_ahalf(&As[0][0], wr,c,g, 1, afr);
    stageB(0, t2, 1); stageA(0, t2, 0);
    BAR(); LGK0(); SP1(); mma_q<1,1>(afr,bfr1,acc); SP0(); BAR();
    BAR(); LGK0(); SP1(); mma_q<1,0>(afr,bfr0,acc); SP0(); VMC6(); BAR();
    read_ahalf(&As[1][0], wr,c,g, 0, afr);
    read_bhalf(&Bs[1][0], wc,c,g, 0, bfr0);
    stageA(0, t2, 1);
    BAR(); LGK0(); SP1(); mma_q<0,0>(afr,bfr0,acc); SP0(); BAR();
    read_bhalf(&Bs[1][0], wc,c,g, 1, bfr1);
    stageB(1, t3, 0);
    BAR(); LGK0(); SP1(); mma_q<0,1>(afr,bfr1,acc); SP0(); BAR();
    read_ahalf(&As[1][0], wr,c,g, 1, afr);
    stageB(1, t3, 1); stageA(1, t3, 0);
    BAR(); LGK0(); SP1(); mma_q<1,1>(afr,bfr1,acc); SP0(); BAR();
    stageA(1, t3, 1);
    BAR(); LGK0(); SP1(); mma_q<1,0>(afr,bfr0,acc); SP0(); VMC8(); BAR();
  }
  {
    read_ahalf(&As[0][0], wr,c,g, 0, afr);
    read_bhalf(&Bs[0][0], wc,c,g, 0, bfr0);
    BAR(); LGK0(); SP1(); mma_q<0,0>(afr,bfr0,acc); SP0(); BAR();
    read_bhalf(&Bs[0][0], wc,c,g, 1, bfr1);
    BAR(); LGK0(); SP1(); mma_q<0,1>(afr,bfr1,acc); SP0(); BAR();
    read_ahalf(&As[0][0], wr,c,g, 1, afr);
    BAR(); LGK0(); SP1(); mma_q<1,1>(afr,bfr1,acc); SP0(); BAR();
    BAR(); LGK0(); SP1(); mma_q<1,0>(afr,bfr0,acc); SP0(); VMC0(); BAR();
    read_ahalf(&As[1][0], wr,c,g, 0, afr);
    read_bhalf(&Bs[1][0], wc,c,g, 0, bfr0);
    BAR(); LGK0(); SP1(); mma_q<0,0>(afr,bfr0,acc); SP0(); BAR();
    read_bhalf(&Bs[1][0], wc,c,g, 1, bfr1);
    BAR(); LGK0(); SP1(); mma_q<0,1>(afr,bfr1,acc); SP0(); BAR();
    read_ahalf(&As[1][0], wr,c,g, 1, afr);
    BAR(); LGK0(); SP1(); mma_q<1,1>(afr,bfr1,acc); SP0(); BAR();
    BAR(); LGK0(); SP1(); mma_q<1,0>(afr,bfr0,acc); SP0(); BAR();
  }

  #pragma unroll
  for (int fa=0; fa<8; ++fa){
    #pragma unroll
    for (int fb=0; fb<4; ++fb){
      f32x4 v = acc[fa][fb];
      #pragma unroll
      for (int rr=0; rr<4; ++rr){
        int row = m0 + wr*128 + fa*16 + g*4 + rr;
        int col = n0 + wc*64  + fb*16 + c;
        float x = v[rr];
        if (MODE == 0){
          x = fminf(fmaxf(x, -8.0f), 8.0f);
          int sel = col >> 12, wi = col & 4095;
          int head = wi >> 7, d = wi & 127;
          int b = row >> 11, s = row & 2047;
          size_t off = ((size_t)(b*NHEAD + head)*SEQ + s)*HDIM + d;
          short* dst = (sel == 0) ? Qb : (sel == 1) ? Kb : Vb;
          dst[off] = f2bf(x);
        } else {
          Of[(size_t)row*HID + col] = x;
        }
      }
    }
  }
}

// ---- RoPE in place on Q and K, vectorized; Q gets *SC2 (scale+log2e fold) ----
__global__ void rope_apply_k(short* __restrict__ Qb, short* __restrict__ Kb,
                             const float* __restrict__ tab){
  int idx = blockIdx.x*blockDim.x + threadIdx.x;
  if (idx >= BH*SEQ*8) return;
  int t = idx & 7;
  int s = (idx >> 3) & (SEQ-1);
  int bh = idx >> 14;
  size_t base = ((size_t)bh*SEQ + s)*HDIM + t*8;
  const float* tb = tab + 2*(s*64 + t*8);
  bf16x8 q1 = *(bf16x8*)(Qb+base), q2 = *(bf16x8*)(Qb+base+64);
  bf16x8 k1 = *(bf16x8*)(Kb+base), k2 = *(bf16x8*)(Kb+base+64);
  bf16x8 o1, o2, p1, p2;
  #pragma unroll
  for (int u=0;u<8;++u){
    float cs = tb[2*u], sn = tb[2*u+1];
    float a = bf2f(q1[u]), b = bf2f(q2[u]);
    o1[u] = f2bf((a*cs - b*sn)*SC2); o2[u] = f2bf((b*cs + a*sn)*SC2);
    a = bf2f(k1[u]); b = bf2f(k2[u]);
    p1[u] = f2bf(a*cs - b*sn); p2[u] = f2bf(b*cs + a*sn);
  }
  *(bf16x8*)(Qb+base)    = o1; *(bf16x8*)(Qb+base+64) = o2;
  *(bf16x8*)(Kb+base)    = p1; *(bf16x8*)(Kb+base+64) = p2;
}

// ---------------- V transpose: [BH][S][HD] -> Vt [BH][HD][S] ----------------
__global__ void transpose_v_k(const short* __restrict__ V, short* __restrict__ Vt){
  __shared__ short t[32][33];
  int bh = blockIdx.z;
  int s0 = blockIdx.x*32, d0 = blockIdx.y*32;
  int tx = threadIdx.x & 31, ty = threadIdx.x >> 5;  // 32 x 8
  const short* src = V + ((size_t)bh*SEQ + s0)*HDIM + d0;
  #pragma unroll
  for (int i=ty;i<32;i+=8) t[i][tx] = src[(size_t)i*HDIM + tx];
  __syncthreads();
  short* dst = Vt + ((size_t)bh*HDIM + d0)*SEQ + s0;
  #pragma unroll
  for (int i=ty;i<32;i+=8) dst[(size_t)i*SEQ + tx] = t[tx][i];
}

// ---- Flash attention, causal, double-buffered; base-2 softmax + defer-rescale ----
__global__ __launch_bounds__(256) void flash_attn_k(
    const short* __restrict__ Qb, const short* __restrict__ Kb,
    const short* __restrict__ Vt, short* __restrict__ attn){
  __shared__ short Ks[2][64*128];   // [kv][d], chunk-swizzled
  __shared__ short Vs[2][128*64];   // [d][kv], chunk-swizzled
  __shared__ short Ps[4][16][72];   // per-wave P, padded stride 72
  int tid = threadIdx.x, lane = tid & 63, w = tid >> 6;
  int g = lane >> 4, c = lane & 15;
  int flat = blockIdx.y*gridDim.x + blockIdx.x;
  int xcd = flat & 7, idx = flat >> 3;
  int bh = xcd + 8*(idx >> 5);
  int qblk = 31 - (idx & 31);       // heavy-first
  int q0 = qblk * 64;
  int qw = q0 + w*16;
  bf16x8 qf[4];
  #pragma unroll
  for (int ks=0;ks<4;++ks)
    qf[ks] = *(const bf16x8*)(Qb + ((size_t)bh*SEQ + qw + c)*HDIM + ks*32 + g*8);
  f32x4 o[8];
  f32x4 zero = {0.f,0.f,0.f,0.f};
  #pragma unroll
  for (int i=0;i<8;++i) o[i] = zero;
  float m_r[4] = {-1e30f,-1e30f,-1e30f,-1e30f};
  float l_r[4] = {0.f,0.f,0.f,0.f};

  auto stage = [&](int j, int b){
    int kv0 = j*64;
    #pragma unroll
    for (int i=0;i<4;++i){
      int e = i*256 + tid;
      int kr = e >> 4, kc = e & 15;
      gload_lds16(Kb + ((size_t)bh*SEQ + kv0 + kr)*HDIM + (size_t)((kc ^ (kr&7))*8),
                  &Ks[b][kr*128 + kc*8]);
      int vr = e >> 3, vc = e & 7;
      gload_lds16(Vt + ((size_t)bh*HDIM + vr)*SEQ + kv0 + (size_t)((vc ^ (vr&7))*8),
                  &Vs[b][vr*64 + vc*8]);
    }
  };

  stage(0, 0);
  __syncthreads();
  int buf = 0;
  for (int j=0;j<=qblk;++j){
    if (j < qblk) stage(j+1, buf^1);

    int kv0 = j*64;
    f32x4 sf[4];
    #pragma unroll
    for (int fj=0;fj<4;++fj) sf[fj] = zero;
    __builtin_amdgcn_s_setprio(1);
    #pragma unroll
    for (int ks=0;ks<4;++ks){
      #pragma unroll
      for (int fj=0;fj<4;++fj){
        int kvrow = fj*16 + c;
        bf16x8 kb = *(const bf16x8*)&Ks[buf][kvrow*128 + (((ks*4+g) ^ (c&7))*8)];
        sf[fj] = __builtin_amdgcn_mfma_f32_16x16x32_bf16(qf[ks], kb, sf[fj], 0,0,0);
      }
    }
    __builtin_amdgcn_s_setprio(0);
    bool diag = (j == qblk);
    float rmax[4];
    #pragma unroll
    for (int rr=0;rr<4;++rr){
      if (diag){
        #pragma unroll
        for (int fj=0;fj<4;++fj)
          if ((kv0 + fj*16 + c) > (qw + g*4 + rr)) sf[fj][rr] = -1e30f;
      }
      float t = fmaxf(fmaxf(sf[0][rr], sf[1][rr]), fmaxf(sf[2][rr], sf[3][rr]));
      t = fmaxf(t, __shfl_xor(t, 1));
      t = fmaxf(t, __shfl_xor(t, 2));
      t = fmaxf(t, __shfl_xor(t, 4));
      t = fmaxf(t, __shfl_xor(t, 8));
      rmax[rr] = t;
    }
    // T13 defer-rescale: skip O/l rescale while per-tile max growth < 8 (base-2)
    bool need = (rmax[0] > m_r[0] + 8.0f) | (rmax[1] > m_r[1] + 8.0f) |
                (rmax[2] > m_r[2] + 8.0f) | (rmax[3] > m_r[3] + 8.0f);
    if (__any(need)){
      float alpha[4];
      #pragma unroll
      for (int rr=0;rr<4;++rr){
        float mnew = fmaxf(m_r[rr], rmax[rr]);
        alpha[rr] = exp2f(m_r[rr] - mnew);
        m_r[rr] = mnew;
        l_r[rr] *= alpha[rr];
      }
      #pragma unroll
      for (int ni=0;ni<8;++ni){
        f32x4 t = o[ni];
        t[0]*=alpha[0]; t[1]*=alpha[1]; t[2]*=alpha[2]; t[3]*=alpha[3];
        o[ni] = t;
      }
    }
    #pragma unroll
    for (int rr=0;rr<4;++rr){
      float ps = 0.f;
      #pragma unroll
      for (int fj=0;fj<4;++fj){
        float p = exp2f(sf[fj][rr] - m_r[rr]);
        sf[fj][rr] = p;
        ps += p;
      }
      ps += __shfl_xor(ps, 1);
      ps += __shfl_xor(ps, 2);
      ps += __shfl_xor(ps, 4);
      ps += __shfl_xor(ps, 8);
      l_r[rr] += ps;
    }
    #pragma unroll
    for (int fj=0;fj<4;++fj)
      #pragma unroll
      for (int rr=0;rr<4;++rr)
        Ps[w][g*4+rr][fj*16+c] = f2bf(sf[fj][rr]);
    __builtin_amdgcn_s_setprio(1);
    #pragma unroll
    for (int ks=0;ks<2;++ks){
      bf16x8 pa = *(const bf16x8*)&Ps[w][c][ks*32 + g*8];
      #pragma unroll
      for (int ni=0;ni<8;++ni){
        int d = ni*16 + c;
        bf16x8 vb = *(const bf16x8*)&Vs[buf][d*64 + (((ks*4+g) ^ (c&7))*8)];
        o[ni] = __builtin_amdgcn_mfma_f32_16x16x32_bf16(pa, vb, o[ni], 0,0,0);
      }
    }
    __builtin_amdgcn_s_setprio(0);
    __syncthreads();
    buf ^= 1;
  }
  int b = bh >> 5, h = bh & 31;
  #pragma unroll
  for (int rr=0;rr<4;++rr){
    float inv = 1.0f / l_r[rr];
    int s = qw + g*4 + rr;
    #pragma unroll
    for (int ni=0;ni<8;++ni){
      int d = ni*16 + c;
      attn[((size_t)(b*SEQ + s))*HID + h*HDIM + d] = f2bf(o[ni][rr] * inv);
    }
  }
}

extern "C" void kernel_launch(void* const* d_in, const int* in_sizes, int n_in,
                              void* d_out, int out_size, void* d_ws, size_t ws_size,
                              hipStream_t stream){
  const float* hs   = (const float*)d_in[0];
  const int*   pos  = (const int*)d_in[1];
  const float* wqkv = (const float*)d_in[2];
  const float* wo   = (const float*)d_in[3];
  float* out = (float*)d_out;
  char* ws = (char*)d_ws;
  size_t off = 0;
  auto alloc = [&](size_t bytes){ void* p = ws + off; off += (bytes + 255) & ~(size_t)255; return p; };
  short* hsb   = (short*)alloc((size_t)MROWS*HID*2);
  short* wqkvb = (short*)alloc((size_t)3*HID*HID*2);
  short* wob   = (short*)alloc((size_t)HID*HID*2);
  short* Qb    = (short*)alloc((size_t)BH*SEQ*HDIM*2);
  short* Kb    = (short*)alloc((size_t)BH*SEQ*HDIM*2);
  short* Vb    = (short*)alloc((size_t)BH*SEQ*HDIM*2);
  short* Vt    = (short*)alloc((size_t)BH*SEQ*HDIM*2);
  short* attn  = (short*)alloc((size_t)MROWS*HID*2);
  float* tab   = (float*)alloc((size_t)SEQ*64*2*4);
  (void)ws_size; (void)in_sizes; (void)n_in; (void)out_size;

  cvt3_bf16<<<2048,256,0,stream>>>(hs, hsb, MROWS*HID/4,
                                   wqkv, wqkvb, 3*HID*HID/4,
                                   wo, wob, HID*HID/4);
  rope_table_k<<<(SEQ*64+255)/256,256,0,stream>>>(pos, tab);
  gemm8r<0><<<dim3(48,16),512,0,stream>>>(hsb, wqkvb, Qb, Kb, Vb, nullptr);
  rope_apply_k<<<(BH*SEQ*8+255)/256,256,0,stream>>>(Qb, Kb, tab);
  transpose_v_k<<<dim3(SEQ/32, HDIM/32, BH),256,0,stream>>>(Vb, Vt);
  flash_attn_k<<<dim3(SEQ/64, BH),256,0,stream>>>(Qb, Kb, Vt, attn);
  gemm8r<1><<<dim3(16,16),512,0,stream>>>(attn, wob, nullptr, nullptr, nullptr, out);
}

// Round 11
// 782.266 us; speedup vs baseline: 1.0860x; 1.0492x over previous
//
#include <hip/hip_runtime.h>
#include <hip/hip_bf16.h>

#define BATCH 2
#define SEQ 2048
#define HID 4096
#define NHEAD 32
#define HDIM 128
#define BH (BATCH*NHEAD)   /* 64 */
#define MROWS (BATCH*SEQ)  /* 4096 */
#define SC2 0.1275187963f   /* (1/sqrt(128)) * log2(e), folded into Q in rope */

typedef __attribute__((ext_vector_type(8))) short bf16x8;
typedef __attribute__((ext_vector_type(4))) float f32x4;

__device__ __forceinline__ float bf2f(short x){
  union { float f; unsigned u; } v; v.u = ((unsigned)(unsigned short)x) << 16; return v.f;
}
__device__ __forceinline__ short f2bf(float f){
  union { float f; unsigned u; } v; v.f = f;
  unsigned r = v.u + 0x7fffu + ((v.u >> 16) & 1u);
  return (short)(r >> 16);
}
__device__ __forceinline__ void gload_lds16(const void* g, void* l){
  __builtin_amdgcn_global_load_lds(
    (const __attribute__((address_space(1))) void*)g,
    (__attribute__((address_space(3))) void*)l, 16, 0, 0);
}

// ---------------- fused f32 -> bf16 convert (3 tensors) ----------------
__global__ void cvt3_bf16(const float* __restrict__ a, short* __restrict__ ao, int na4,
                          const float* __restrict__ b, short* __restrict__ bo, int nb4,
                          const float* __restrict__ cc, short* __restrict__ co, int nc4){
  int i = blockIdx.x*blockDim.x + threadIdx.x;
  int stride = gridDim.x*blockDim.x;
  int tot = na4 + nb4 + nc4;
  for (; i < tot; i += stride){
    const float* src; short* dst; int k = i;
    if (k < na4){ src=a; dst=ao; }
    else if (k < na4+nb4){ k -= na4; src=b; dst=bo; }
    else { k -= na4+nb4; src=cc; dst=co; }
    float4 v = ((const float4*)src)[k];
    short4 o;
    o.x = f2bf(v.x); o.y = f2bf(v.y); o.z = f2bf(v.z); o.w = f2bf(v.w);
    ((short4*)dst)[k] = o;
  }
}

// ---------------- RoPE cos/sin table ----------------
__global__ void rope_table_k(const int* __restrict__ pos, float* __restrict__ tab){
  int idx = blockIdx.x*blockDim.x + threadIdx.x;
  if (idx >= SEQ*64) return;
  int s = idx >> 6, d = idx & 63;
  float p = (float)pos[s];
  float inv = exp2f(-(float)d * (13.287712379549449f/64.0f)); // 10000^(-d/64)
  float ang = p * inv;
  tab[2*idx]   = cosf(ang);
  tab[2*idx+1] = sinf(ang);
}

// ===== 256x256 8-phase GEMM, minimal LDS reads (24 b128/K-tile), vmcnt(6/8) =====
// (round-5 known-good: 395us QKV, MfmaUtil 45.5, 0 bank conflicts, no spill.
//  Schedule is a verified local optimum: r7 read-ahead spilled, r9 {8,0,8,8} lost 7%.)
template<int W>
__device__ __forceinline__ void stage_half(const short* __restrict__ gsrc, int ldg,
                                           short* lds, int tid, int h){
  #pragma unroll
  for (int li=0; li<2; ++li){
    int e16 = li*512 + tid;
    int rs = e16 >> 3, ck = e16 & 7;
    int r = ((rs/W)*2 + h)*W + (rs%W);
    gload_lds16(gsrc + (size_t)r*ldg + ((ck ^ (r&7))<<3),
                lds + r*64 + ck*8);
  }
}

__device__ __forceinline__ void read_ahalf(const short* Asb, int wr, int c, int g,
                                           int Mh, bf16x8 (&afr)[4][2]){
  #pragma unroll
  for (int mi=0; mi<4; ++mi){
    int row = wr*128 + (Mh*4+mi)*16 + c;
    const char* bp = (const char*)Asb + row*128;
    #pragma unroll
    for (int kk=0; kk<2; ++kk)
      afr[mi][kk] = *(const bf16x8*)(bp + ((kk*64 + g*16) ^ ((row&7)<<4)));
  }
}
__device__ __forceinline__ void read_bhalf(const short* Bsb, int wc, int c, int g,
                                           int Nh, bf16x8 (&bfr)[2][2]){
  #pragma unroll
  for (int ni=0; ni<2; ++ni){
    int row = wc*64 + (Nh*2+ni)*16 + c;
    const char* bp = (const char*)Bsb + row*128;
    #pragma unroll
    for (int kk=0; kk<2; ++kk)
      bfr[ni][kk] = *(const bf16x8*)(bp + ((kk*64 + g*16) ^ ((row&7)<<4)));
  }
}
template<int MH, int NHH>
__device__ __forceinline__ void mma_q(bf16x8 (&afr)[4][2], bf16x8 (&bfr)[2][2],
                                      f32x4 (&acc)[8][4]){
  #pragma unroll
  for (int kk=0; kk<2; ++kk)
    #pragma unroll
    for (int mi=0; mi<4; ++mi)
      #pragma unroll
      for (int ni=0; ni<2; ++ni)
        acc[MH*4+mi][NHH*2+ni] = __builtin_amdgcn_mfma_f32_16x16x32_bf16(
            afr[mi][kk], bfr[ni][kk], acc[MH*4+mi][NHH*2+ni], 0,0,0);
}

#define BAR()  asm volatile("s_barrier" ::: "memory")
#define LGK0() asm volatile("s_waitcnt lgkmcnt(0)" ::: "memory")
#define VMC6() asm volatile("s_waitcnt vmcnt(6)" ::: "memory")
#define VMC8() asm volatile("s_waitcnt vmcnt(8)" ::: "memory")
#define VMC0() asm volatile("s_waitcnt vmcnt(0)" ::: "memory")
#define SP1()  __builtin_amdgcn_s_setprio(1)
#define SP0()  __builtin_amdgcn_s_setprio(0)

// MODE 0: QKV proj -> clip +-8 -> scatter bf16 into Q/K/V [BH][S][HD]
// MODE 1: O proj -> f32 row-major out
template<int MODE>
__global__ __launch_bounds__(512, 2) void gemm8r(
    const short* __restrict__ A, const short* __restrict__ Bw,
    short* __restrict__ Qb, short* __restrict__ Kb, short* __restrict__ Vb,
    float* __restrict__ Of){
  __shared__ __align__(16) short As[2][256*64];
  __shared__ __align__(16) short Bs[2][256*64];
  const int K = HID;
  int tid = threadIdx.x, lane = tid & 63, w = tid >> 6;
  int wr = w >> 2, wc = w & 3, g = lane >> 4, c = lane & 15;
  int gx = gridDim.x;
  int nwg = gx * gridDim.y;
  int bid = blockIdx.y*gx + blockIdx.x;
  int cpx = nwg >> 3;
  int swz = (bid & 7)*cpx + (bid >> 3);
  int m0 = (swz / gx) * 256, n0 = (swz % gx) * 256;

  const short* Abase = A  + (size_t)m0*K;
  const short* Bbase = Bw + (size_t)n0*K;
  auto stageA = [&](int buf, int kt, int h){
    stage_half<64>(Abase + kt*64, K, &As[buf][0], tid, h);
  };
  auto stageB = [&](int buf, int kt, int h){
    stage_half<32>(Bbase + kt*64, K, &Bs[buf][0], tid, h);
  };

  f32x4 acc[8][4];
  f32x4 zero = {0.f,0.f,0.f,0.f};
  #pragma unroll
  for (int i=0;i<8;++i)
    #pragma unroll
    for (int j=0;j<4;++j) acc[i][j] = zero;
  bf16x8 afr[4][2], bfr0[2][2], bfr1[2][2];

  stageB(0,0,0); stageB(0,0,1); stageA(0,0,0); stageA(0,0,1);
  stageB(1,1,0); stageB(1,1,1); stageA(1,1,0); stageA(1,1,1);
  VMC8();
  BAR();

  const int NITER = K/128;  // 32 iterations, 2 K-tiles each
  for (int i = 0; i < NITER-1; ++i){
    int t2 = 2*i+2, t3 = 2*i+3;
    read_ahalf(&As[0][0], wr,c,g, 0, afr);
    read_bhalf(&Bs[0][0], wc,c,g, 0, bfr0);
    BAR(); LGK0(); SP1(); mma_q<0,0>(afr,bfr0,acc); SP0(); BAR();
    read_bhalf(&Bs[0][0], wc,c,g, 1, bfr1);
    stageB(0, t2, 0);
    BAR(); LGK0(); SP1(); mma_q<0,1>(afr,bfr1,acc); SP0(); BAR();
    read_ahalf(&As[0][0], wr,c,g, 1, afr);
    stageB(0, t2, 1); stageA(0, t2, 0);
    BAR(); LGK0(); SP1(); mma_q<1,1>(afr,bfr1,acc); SP0(); BAR();
    BAR(); LGK0(); SP1(); mma_q<1,0>(afr,bfr0,acc); SP0(); VMC6(); BAR();
    read_ahalf(&As[1][0], wr,c,g, 0, afr);
    read_bhalf(&Bs[1][0], wc,c,g, 0, bfr0);
    stageA(0, t2, 1);
    BAR(); LGK0(); SP1(); mma_q<0,0>(afr,bfr0,acc); SP0(); BAR();
    read_bhalf(&Bs[1][0], wc,c,g, 1, bfr1);
    stageB(1, t3, 0);
    BAR(); LGK0(); SP1(); mma_q<0,1>(afr,bfr1,acc); SP0(); BAR();
    read_ahalf(&As[1][0], wr,c,g, 1, afr);
    stageB(1, t3, 1); stageA(1, t3, 0);
    BAR(); LGK0(); SP1(); mma_q<1,1>(afr,bfr1,acc); SP0(); BAR();
    stageA(1, t3, 1);
    BAR(); LGK0(); SP1(); mma_q<1,0>(afr,bfr0,acc); SP0(); VMC8(); BAR();
  }
  {
    read_ahalf(&As[0][0], wr,c,g, 0, afr);
    read_bhalf(&Bs[0][0], wc,c,g, 0, bfr0);
    BAR(); LGK0(); SP1(); mma_q<0,0>(afr,bfr0,acc); SP0(); BAR();
    read_bhalf(&Bs[0][0], wc,c,g, 1, bfr1);
    BAR(); LGK0(); SP1(); mma_q<0,1>(afr,bfr1,acc); SP0(); BAR();
    read_ahalf(&As[0][0], wr,c,g, 1, afr);
    BAR(); LGK0(); SP1(); mma_q<1,1>(afr,bfr1,acc); SP0(); BAR();
    BAR(); LGK0(); SP1(); mma_q<1,0>(afr,bfr0,acc); SP0(); VMC0(); BAR();
    read_ahalf(&As[1][0], wr,c,g, 0, afr);
    read_bhalf(&Bs[1][0], wc,c,g, 0, bfr0);
    BAR(); LGK0(); SP1(); mma_q<0,0>(afr,bfr0,acc); SP0(); BAR();
    read_bhalf(&Bs[1][0], wc,c,g, 1, bfr1);
    BAR(); LGK0(); SP1(); mma_q<0,1>(afr,bfr1,acc); SP0(); BAR();
    read_ahalf(&As[1][0], wr,c,g, 1, afr);
    BAR(); LGK0(); SP1(); mma_q<1,1>(afr,bfr1,acc); SP0(); BAR();
    BAR(); LGK0(); SP1(); mma_q<1,0>(afr,bfr0,acc); SP0(); BAR();
  }

  #pragma unroll
  for (int fa=0; fa<8; ++fa){
    #pragma unroll
    for (int fb=0; fb<4; ++fb){
      f32x4 v = acc[fa][fb];
      #pragma unroll
      for (int rr=0; rr<4; ++rr){
        int row = m0 + wr*128 + fa*16 + g*4 + rr;
        int col = n0 + wc*64  + fb*16 + c;
        float x = v[rr];
        if (MODE == 0){
          x = fminf(fmaxf(x, -8.0f), 8.0f);
          int sel = col >> 12, wi = col & 4095;
          int head = wi >> 7, d = wi & 127;
          int b = row >> 11, s = row & 2047;
          size_t off = ((size_t)(b*NHEAD + head)*SEQ + s)*HDIM + d;
          short* dst = (sel == 0) ? Qb : (sel == 1) ? Kb : Vb;
          dst[off] = f2bf(x);
        } else {
          Of[(size_t)row*HID + col] = x;
        }
      }
    }
  }
}

// ---- RoPE in place on Q and K, vectorized; Q gets *SC2 (scale+log2e fold) ----
__global__ void rope_apply_k(short* __restrict__ Qb, short* __restrict__ Kb,
                             const float* __restrict__ tab){
  int idx = blockIdx.x*blockDim.x + threadIdx.x;
  if (idx >= BH*SEQ*8) return;
  int t = idx & 7;
  int s = (idx >> 3) & (SEQ-1);
  int bh = idx >> 14;
  size_t base = ((size_t)bh*SEQ + s)*HDIM + t*8;
  const float* tb = tab + 2*(s*64 + t*8);
  bf16x8 q1 = *(bf16x8*)(Qb+base), q2 = *(bf16x8*)(Qb+base+64);
  bf16x8 k1 = *(bf16x8*)(Kb+base), k2 = *(bf16x8*)(Kb+base+64);
  bf16x8 o1, o2, p1, p2;
  #pragma unroll
  for (int u=0;u<8;++u){
    float cs = tb[2*u], sn = tb[2*u+1];
    float a = bf2f(q1[u]), b = bf2f(q2[u]);
    o1[u] = f2bf((a*cs - b*sn)*SC2); o2[u] = f2bf((b*cs + a*sn)*SC2);
    a = bf2f(k1[u]); b = bf2f(k2[u]);
    p1[u] = f2bf(a*cs - b*sn); p2[u] = f2bf(b*cs + a*sn);
  }
  *(bf16x8*)(Qb+base)    = o1; *(bf16x8*)(Qb+base+64) = o2;
  *(bf16x8*)(Kb+base)    = p1; *(bf16x8*)(Kb+base+64) = p2;
}

// ---------------- V transpose: [BH][S][HD] -> Vt [BH][HD][S] ----------------
__global__ void transpose_v_k(const short* __restrict__ V, short* __restrict__ Vt){
  __shared__ short t[32][33];
  int bh = blockIdx.z;
  int s0 = blockIdx.x*32, d0 = blockIdx.y*32;
  int tx = threadIdx.x & 31, ty = threadIdx.x >> 5;  // 32 x 8
  const short* src = V + ((size_t)bh*SEQ + s0)*HDIM + d0;
  #pragma unroll
  for (int i=ty;i<32;i+=8) t[i][tx] = src[(size_t)i*HDIM + tx];
  __syncthreads();
  short* dst = Vt + ((size_t)bh*HDIM + d0)*SEQ + s0;
  #pragma unroll
  for (int i=ty;i<32;i+=8) dst[(size_t)i*SEQ + tx] = t[tx][i];
}

// ---- Flash attention, causal, double-buffered; SWAPPED QK^T (S^T in regs):
// lane (g,c) holds S[q=c][kv=fj*16+g*4+rr] -> row softmax = in-reg tree + 2 shfls.
// Ps[i][j] = P[q=i][kv=j] invariant preserved -> PV + O-write unchanged. ----
__global__ __launch_bounds__(256) void flash_attn_k(
    const short* __restrict__ Qb, const short* __restrict__ Kb,
    const short* __restrict__ Vt, short* __restrict__ attn){
  __shared__ short Ks[2][64*128];   // [kv][d], chunk-swizzled
  __shared__ short Vs[2][128*64];   // [d][kv], chunk-swizzled
  __shared__ short Ps[4][16][72];   // per-wave P, padded stride 72
  int tid = threadIdx.x, lane = tid & 63, w = tid >> 6;
  int g = lane >> 4, c = lane & 15;
  int flat = blockIdx.y*gridDim.x + blockIdx.x;
  int xcd = flat & 7, idx = flat >> 3;
  int bh = xcd + 8*(idx >> 5);
  int qblk = 31 - (idx & 31);       // heavy-first
  int q0 = qblk * 64;
  int qw = q0 + w*16;
  bf16x8 qf[4];
  #pragma unroll
  for (int ks=0;ks<4;++ks)
    qf[ks] = *(const bf16x8*)(Qb + ((size_t)bh*SEQ + qw + c)*HDIM + ks*32 + g*8);
  f32x4 o[8];
  f32x4 zero = {0.f,0.f,0.f,0.f};
  #pragma unroll
  for (int i=0;i<8;++i) o[i] = zero;
  float m_r = -1e30f;   // running max for q-row = qw + c (scalar per lane)
  float l_r = 0.f;      // running denom

  auto stage = [&](int j, int b){
    int kv0 = j*64;
    #pragma unroll
    for (int i=0;i<4;++i){
      int e = i*256 + tid;
      int kr = e >> 4, kc = e & 15;
      gload_lds16(Kb + ((size_t)bh*SEQ + kv0 + kr)*HDIM + (size_t)((kc ^ (kr&7))*8),
                  &Ks[b][kr*128 + kc*8]);
      int vr = e >> 3, vc = e & 7;
      gload_lds16(Vt + ((size_t)bh*HDIM + vr)*SEQ + kv0 + (size_t)((vc ^ (vr&7))*8),
                  &Vs[b][vr*64 + vc*8]);
    }
  };

  stage(0, 0);
  __syncthreads();
  int buf = 0;
  for (int j=0;j<=qblk;++j){
    if (j < qblk) stage(j+1, buf^1);

    int kv0 = j*64;
    f32x4 sf[4];
    #pragma unroll
    for (int fj=0;fj<4;++fj) sf[fj] = zero;
    __builtin_amdgcn_s_setprio(1);
    #pragma unroll
    for (int ks=0;ks<4;++ks){
      #pragma unroll
      for (int fj=0;fj<4;++fj){
        int kvrow = fj*16 + c;
        bf16x8 kb = *(const bf16x8*)&Ks[buf][kvrow*128 + (((ks*4+g) ^ (c&7))*8)];
        // SWAPPED operands: S^T = K·Q^T
        sf[fj] = __builtin_amdgcn_mfma_f32_16x16x32_bf16(kb, qf[ks], sf[fj], 0,0,0);
      }
    }
    __builtin_amdgcn_s_setprio(0);
    if (j == qblk){
      int q = qw + c;
      #pragma unroll
      for (int fj=0;fj<4;++fj)
        #pragma unroll
        for (int rr=0;rr<4;++rr)
          if ((kv0 + fj*16 + g*4 + rr) > q) sf[fj][rr] = -1e30f;
    }
    // row max: in-register tree + 2 cross-g shfls
    f32x4 t4;
    #pragma unroll
    for (int rr=0;rr<4;++rr)
      t4[rr] = fmaxf(fmaxf(sf[0][rr], sf[1][rr]), fmaxf(sf[2][rr], sf[3][rr]));
    float rmax = fmaxf(fmaxf(t4[0], t4[1]), fmaxf(t4[2], t4[3]));
    rmax = fmaxf(rmax, __shfl_xor(rmax, 16));
    rmax = fmaxf(rmax, __shfl_xor(rmax, 32));
    // T13 defer-rescale (base-2, threshold 8)
    if (__any(rmax > m_r + 8.0f)){
      float mnew = fmaxf(m_r, rmax);
      float alpha = exp2f(m_r - mnew);
      m_r = mnew;
      l_r *= alpha;
      float a4[4];
      #pragma unroll
      for (int rr=0;rr<4;++rr) a4[rr] = __shfl(alpha, g*4 + rr);  // alpha of q-row g*4+rr
      #pragma unroll
      for (int ni=0;ni<8;++ni){
        f32x4 t = o[ni];
        t[0]*=a4[0]; t[1]*=a4[1]; t[2]*=a4[2]; t[3]*=a4[3];
        o[ni] = t;
      }
    }
    // exp2 + in-reg sum + 2 shfls
    float ps;
    {
      f32x4 s4;
      #pragma unroll
      for (int fj=0;fj<4;++fj)
        #pragma unroll
        for (int rr=0;rr<4;++rr)
          sf[fj][rr] = exp2f(sf[fj][rr] - m_r);
      #pragma unroll
      for (int rr=0;rr<4;++rr)
        s4[rr] = (sf[0][rr] + sf[1][rr]) + (sf[2][rr] + sf[3][rr]);
      ps = (s4[0] + s4[1]) + (s4[2] + s4[3]);
      ps += __shfl_xor(ps, 16);
      ps += __shfl_xor(ps, 32);
    }
    l_r += ps;
    // P -> Ps (Ps[i][j] = P[q=i][kv=j]; our lane holds q=c, kv=fj*16+g*4+rr)
    #pragma unroll
    for (int fj=0;fj<4;++fj)
      #pragma unroll
      for (int rr=0;rr<4;++rr)
        Ps[w][c][fj*16 + g*4 + rr] = f2bf(sf[fj][rr]);
    __builtin_amdgcn_s_setprio(1);
    #pragma unroll
    for (int ks=0;ks<2;++ks){
      bf16x8 pa = *(const bf16x8*)&Ps[w][c][ks*32 + g*8];
      #pragma unroll
      for (int ni=0;ni<8;++ni){
        int d = ni*16 + c;
        bf16x8 vb = *(const bf16x8*)&Vs[buf][d*64 + (((ks*4+g) ^ (c&7))*8)];
        o[ni] = __builtin_amdgcn_mfma_f32_16x16x32_bf16(pa, vb, o[ni], 0,0,0);
      }
    }
    __builtin_amdgcn_s_setprio(0);
    __syncthreads();
    buf ^= 1;
  }
  int b = bh >> 5, h = bh & 31;
  float inv = 1.0f / l_r;
  float inv4[4];
  #pragma unroll
  for (int rr=0;rr<4;++rr) inv4[rr] = __shfl(inv, g*4 + rr);  // inv of q-row g*4+rr
  #pragma unroll
  for (int rr=0;rr<4;++rr){
    int s = qw + g*4 + rr;
    #pragma unroll
    for (int ni=0;ni<8;++ni){
      int d = ni*16 + c;
      attn[((size_t)(b*SEQ + s))*HID + h*HDIM + d] = f2bf(o[ni][rr] * inv4[rr]);
    }
  }
}

extern "C" void kernel_launch(void* const* d_in, const int* in_sizes, int n_in,
                              void* d_out, int out_size, void* d_ws, size_t ws_size,
                              hipStream_t stream){
  const float* hs   = (const float*)d_in[0];
  const int*   pos  = (const int*)d_in[1];
  const float* wqkv = (const float*)d_in[2];
  const float* wo   = (const float*)d_in[3];
  float* out = (float*)d_out;
  char* ws = (char*)d_ws;
  size_t off = 0;
  auto alloc = [&](size_t bytes){ void* p = ws + off; off += (bytes + 255) & ~(size_t)255; return p; };
  short* hsb   = (short*)alloc((size_t)MROWS*HID*2);
  short* wqkvb = (short*)alloc((size_t)3*HID*HID*2);
  short* wob   = (short*)alloc((size_t)HID*HID*2);
  short* Qb    = (short*)alloc((size_t)BH*SEQ*HDIM*2);
  short* Kb    = (short*)alloc((size_t)BH*SEQ*HDIM*2);
  short* Vb    = (short*)alloc((size_t)BH*SEQ*HDIM*2);
  short* Vt    = (short*)alloc((size_t)BH*SEQ*HDIM*2);
  short* attn  = (short*)alloc((size_t)MROWS*HID*2);
  float* tab   = (float*)alloc((size_t)SEQ*64*2*4);
  (void)ws_size; (void)in_sizes; (void)n_in; (void)out_size;

  cvt3_bf16<<<2048,256,0,stream>>>(hs, hsb, MROWS*HID/4,
                                   wqkv, wqkvb, 3*HID*HID/4,
                                   wo, wob, HID*HID/4);
  rope_table_k<<<(SEQ*64+255)/256,256,0,stream>>>(pos, tab);
  gemm8r<0><<<dim3(48,16),512,0,stream>>>(hsb, wqkvb, Qb, Kb, Vb, nullptr);
  rope_apply_k<<<(BH*SEQ*8+255)/256,256,0,stream>>>(Qb, Kb, tab);
  transpose_v_k<<<dim3(SEQ/32, HDIM/32, BH),256,0,stream>>>(Vb, Vt);
  flash_attn_k<<<dim3(SEQ/64, BH),256,0,stream>>>(Qb, Kb, Vt, attn);
  gemm8r<1><<<dim3(16,16),512,0,stream>>>(attn, wob, nullptr, nullptr, nullptr, out);
}